// Round 19
// baseline (176.290 us; speedup 1.0000x reference)
//
#include <hip/hip_runtime.h>
#include <hip/hip_bf16.h>

// GNNFeatureExtractor: B=512, N=400 nodes, E_DIM=128, hidden 256.
// Contract (established R0-R4): inputs f32 (edge_index int32), output f32.
// R19 = R18 + ONE lever: kB2 w1t b-frags hoisted ABOVE barriers (half-0's 8
// frags at kernel entry, half-1's 8 after the phase-2 barrier) — structural
// prefetch the scheduler cannot sink (R14/R15 showed in-loop prefetch gets
// re-serialized). Accumulation order unchanged. Everything else = R18.
#define NB 400
#define BB 512
#define ROWS 64      // rows (n-major) per kB2 block
#define KSTR2 136    // uB row stride in bf16 (128 cols + 8 pad, 16B-aligned)
#define KF   24      // fTb row stride in bf16 (48B rows)
#define KS2  136     // xsb row stride in bf16 (kE)

typedef short  bf16x8 __attribute__((ext_vector_type(8)));   // 8 bf16 = 4 VGPRs
typedef float  f32x16 __attribute__((ext_vector_type(16)));
typedef float  f32x4  __attribute__((ext_vector_type(4)));

// ---- workspace layout (bytes), total ~17.9 MB ----
static constexpr size_t O_FEAT  = 0;            // f32 [400*512*16]  13,107,200
static constexpr size_t O_XPK   = 13107200;     // f32 [512*16*128]   4,194,304 packed masked x_pre
static constexpr size_t O_STATS = 17301504;     // f32 sum1/sq1/sum2/sq2 [400] each (sum2/sq2 used)
static constexpr size_t O_AB    = 17307904;     // f32 a1/b1v [400] each
static constexpr size_t O_CS1   = 17314304;     // f32 cs1[128]
static constexpr size_t O_MCNT  = 17314816;     // int mcount[512]
static constexpr size_t O_MLIST = 17316864;     // int mlist[512*16]
static constexpr size_t O_MDINV = 17349632;     // f32 mdinv[512*16]
static constexpr size_t O_MECNT = 17382400;     // int mecnt[512]
static constexpr size_t O_MEDGE = 17384448;     // int medge[512*64]
static constexpr size_t O_LOCG  = 17515520;     // u8  locg2[400*512] TRANSPOSED (255 = unmasked)
static constexpr size_t O_W1T   = 17720320;     // bf16 [128][256] transposed W1, 65,536
static constexpr size_t O_W0TE  = 17785856;     // bf16 [256][16] W0^T extended (k15=b0), 8,192
static constexpr size_t O_WCT   = 17794048;     // bf16 [2][128n][128k] transposed Wc, 65,536

// ---------------- Kernel TA: fused kT + kA + cs1 + stats-zero ----------------
__global__ __launch_bounds__(256) void kTA(const float* __restrict__ agvs,
                                           const float* __restrict__ nodes,
                                           const int* __restrict__ ei, int E,
                                           float* __restrict__ feat,
                                           int* __restrict__ mcount, int* __restrict__ mlist,
                                           float* __restrict__ mdinv, int* __restrict__ mecnt,
                                           int* __restrict__ medge,
                                           unsigned char* __restrict__ locg2,
                                           const float* __restrict__ W1,
                                           const float* __restrict__ W0,
                                           const float* __restrict__ b0,
                                           const float* __restrict__ Wc,
                                           short* __restrict__ w1t,
                                           short* __restrict__ w0te,
                                           short* __restrict__ wct,
                                           float* __restrict__ cs1,
                                           float* __restrict__ zstats)   // sum2 base, 800 f32
{
    const int t = threadIdx.x;
    if (blockIdx.x >= 512) {
        if (blockIdx.x < 784) {
            int i = (blockIdx.x - 512) * 256 + t;
            if (i < 32768) {
                int n = i >> 8, k = i & 255;
                __hip_bfloat16 h = __float2bfloat16(W1[k * 128 + n]);
                w1t[i] = *reinterpret_cast<short*>(&h);
            } else if (i < 36864) {
                int i2 = i - 32768;
                int c = i2 >> 4, k = i2 & 15;
                float v = (k == 15) ? b0[c] : W0[k * 256 + c];
                __hip_bfloat16 h = __float2bfloat16(v);
                w0te[i2] = *reinterpret_cast<short*>(&h);
            } else {
                int i2 = i - 36864;
                int it = i2 >> 14, rem = i2 & 16383, n = rem >> 7, k = rem & 127;
                __hip_bfloat16 h = __float2bfloat16(Wc[it * 16384 + k * 128 + n]);
                wct[i2] = *reinterpret_cast<short*>(&h);
            }
        } else {
            if (t < 128) {
                float s = 0.f;
                for (int c = 0; c < 256; c++) s += W1[c * 128 + t];
                cs1[t] = s;
            } else {
                for (int j = t - 128; j < 800; j += 128) zstats[j] = 0.f;
            }
        }
        return;
    }

    // ---- kA body ----
    __shared__ float nod[2 * NB];
    __shared__ float as_[160];
    __shared__ float fs[NB * 16];
    __shared__ int   idxs[70];
    __shared__ int   m0[NB], m1[NB], deg[NB], loc[NB];
    __shared__ unsigned long long bal[7];
    __shared__ int   pre[8];
    __shared__ int   ecnt;
    const int b = blockIdx.x;

    for (int i = t; i < 2 * NB; i += 256) nod[i] = nodes[i];
    for (int i = t; i < 160; i += 256)    as_[i] = agvs[b * 160 + i];
    for (int i = t; i < NB * 16; i += 256) fs[i] = 0.f;
    for (int i = t; i < NB; i += 256) m0[i] = 0;
    __syncthreads();

    // 70 argmins: strict '<' = np.argmin first-min.
    if (t < 70) {
        float cx, cy;
        if (t < 7) { cx = as_[2 + 2 * t]; cy = as_[3 + 2 * t]; }
        else { int a = (t - 7) / 7, k = (t - 7) % 7;
               cx = as_[16 * (a + 1) + 2 + 2 * k]; cy = as_[16 * (a + 1) + 3 + 2 * k]; }
        float bd = 3.4e38f; int bi = 0;
        for (int n = 0; n < NB; n++) {
            float dx = __fsub_rn(cx, nod[2 * n]);
            float dy = __fsub_rn(cy, nod[2 * n + 1]);
            float d  = __fadd_rn(__fmul_rn(dx, dx), __fmul_rn(dy, dy));
            if (d < bd) { bd = d; bi = n; }
        }
        idxs[t] = bi;
    }
    for (int n = t; n < NB; n += 256) {
        float dx = __fsub_rn(nod[2 * n],     as_[6]);
        float dy = __fsub_rn(nod[2 * n + 1], as_[7]);
        fs[n * 16 + 14] = __fsqrt_rn(__fadd_rn(__fmul_rn(dx, dx), __fmul_rn(dy, dy)));
    }
    __syncthreads();
    if (t < 70) {
        int col = (t < 7) ? t : 7 + ((t - 7) % 7);
        atomicAdd(&fs[idxs[t] * 16 + col], 1.0f);
    }
    if (t == 0) { m0[idxs[1]] = 1; ecnt = 0; }
    __syncthreads();

    for (int i = t; i < NB * 16; i += 256) {
        int n = i >> 4, k = i & 15;
        feat[(size_t)((n << 9) + b) * 16 + k] = fs[i];
    }

    for (int i = t; i < NB; i += 256) m1[i] = m0[i];
    __syncthreads();
    for (int e = t; e < E; e += 256) { int r = ei[e], c = ei[E + e]; if (m0[c]) m1[r] = 1; }
    __syncthreads();
    for (int i = t; i < NB; i += 256) m0[i] = m1[i];
    __syncthreads();
    for (int e = t; e < E; e += 256) { int r = ei[e], c = ei[E + e]; if (m1[c]) m0[r] = 1; }
    __syncthreads();
    for (int i = t; i < NB; i += 256) deg[i] = m0[i];
    __syncthreads();
    for (int e = t; e < E; e += 256) {
        int r = ei[e], c = ei[E + e];
        if (m0[r] && m0[c]) atomicAdd(&deg[c], 1);
    }
    __syncthreads();

    // parallel compaction via wave ballots
    for (int base = 0; base < 448; base += 256) {
        int i = base + t;
        bool m = (i < NB) && (m0[i] != 0);
        unsigned long long bm = __ballot(m);
        if ((t & 63) == 0 && (i >> 6) < 7) bal[i >> 6] = bm;
    }
    __syncthreads();
    if (t == 0) {
        int acc = 0;
        for (int c = 0; c < 7; c++) { pre[c] = acc; acc += __popcll(bal[c]); }
        mcount[b] = acc;
    }
    __syncthreads();
    for (int i = t; i < NB; i += 256) {
        if (m0[i]) {
            int c = i >> 6, l = i & 63;
            int rank = pre[c] + __popcll(bal[c] & ((1ull << l) - 1ull));
            loc[i] = rank;
            mlist[b * 16 + rank] = i;
            int d = deg[i]; if (d < 1) d = 1;
            mdinv[b * 16 + rank] = 1.0f / __fsqrt_rn((float)d);
        }
    }
    __syncthreads();
    for (int i = t; i < NB; i += 256)
        locg2[(size_t)i * 512 + b] = m0[i] ? (unsigned char)loc[i] : (unsigned char)255;
    for (int e = t; e < E; e += 256) {
        int r = ei[e], c = ei[E + e];
        if (m0[r] && m0[c]) {
            int s = atomicAdd(&ecnt, 1);
            if (s < 64) medge[b * 64 + s] = loc[r] | (loc[c] << 8);
        }
    }
    __syncthreads();
    if (t == 0) mecnt[b] = ecnt;
}

// ---------------- Kernel B1 (R13): BN1 stats via MFMA + inline BN1 affine ----------------
__global__ __launch_bounds__(256) void kB1(const float* __restrict__ feat,
                                           const short* __restrict__ w0te,
                                           const float* __restrict__ g1, const float* __restrict__ be1,
                                           float* __restrict__ a1, float* __restrict__ b1v)
{
    __shared__ __align__(16) short fTb[512 * KF];   // 24,576 B
    __shared__ float red[8];
    const int n = blockIdx.x, t = threadIdx.x;
    for (int i = t; i < 512 * 8; i += 256) {
        int r = i >> 3, kk = (i & 7) << 1;
        float2 v = *(const float2*)&feat[(size_t)n * 8192 + r * 16 + kk];
        if (kk == 14) v.y = 1.0f;
        __hip_bfloat16 h0 = __float2bfloat16(v.x), h1 = __float2bfloat16(v.y);
        unsigned int pk = (unsigned int)(unsigned short)*reinterpret_cast<short*>(&h0) |
                          ((unsigned int)(unsigned short)*reinterpret_cast<short*>(&h1) << 16);
        *(unsigned int*)&fTb[r * KF + kk] = pk;
    }
    __syncthreads();

    const int w = t >> 6, l = t & 63, lm = l & 31, q = l >> 5;
    bf16x8 afr[8];
#pragma unroll
    for (int ct = 0; ct < 8; ct++)
        afr[ct] = *(const bf16x8*)&w0te[((ct << 5) + lm) * 16 + (q << 3)];

    float s = 0.f, q2 = 0.f;
#pragma unroll
    for (int ch = 0; ch < 4; ch++) {
        const int row = (((w << 2) + ch) << 5) + lm;
        bf16x8 bfr = *(const bf16x8*)&fTb[row * KF + (q << 3)];
#pragma unroll
        for (int ct = 0; ct < 8; ct++) {
            f32x16 ua = {0.f, 0.f, 0.f, 0.f, 0.f, 0.f, 0.f, 0.f,
                         0.f, 0.f, 0.f, 0.f, 0.f, 0.f, 0.f, 0.f};
            ua = __builtin_amdgcn_mfma_f32_32x32x16_bf16(afr[ct], bfr, ua, 0, 0, 0);
#pragma unroll
            for (int r = 0; r < 16; r++) {
                float x = fmaxf(ua[r], 0.f);
                s += x; q2 = fmaf(x, x, q2);
            }
        }
    }
    for (int off = 32; off > 0; off >>= 1) { s += __shfl_down(s, off, 64); q2 += __shfl_down(q2, off, 64); }
    if (l == 0) { red[w] = s; red[4 + w] = q2; }
    __syncthreads();
    if (t == 0) {
        float S = red[0] + red[1] + red[2] + red[3];
        float Q = red[4] + red[5] + red[6] + red[7];
        const float cnt = 512.f * 256.f;
        float m = S / cnt;
        float v = fmaxf(Q / cnt - m * m, 0.f);
        float a = g1[n] / sqrtf(v + 1e-5f);
        a1[n]  = a;
        b1v[n] = be1[n] - m * a;
    }
}

// ---------------- Kernel B2 (R19): 64-row, 2 chains, K-split, barrier-hoisted b-frags ----------------
__global__ __launch_bounds__(256, 4) void kB2(const float* __restrict__ feat,
                                           const short* __restrict__ w0te,
                                           const short* __restrict__ w1t,
                                           const float* __restrict__ b1,
                                           const float* __restrict__ a1g, const float* __restrict__ b1vg,
                                           const float* __restrict__ cs1,
                                           const unsigned char* __restrict__ locg2,
                                           float* __restrict__ xpk,
                                           float* __restrict__ sum2, float* __restrict__ sumsq2)
{
    __shared__ __align__(16) short fTb[ROWS * KF];     // 3,072 B
    __shared__ __align__(16) short uB[ROWS * KSTR2];   // 17,408 B (one K-half of u)
    __shared__ unsigned char lcs[ROWS];
    __shared__ float red[8];
    const int t = threadIdx.x;
    const size_t r0 = (size_t)blockIdx.x * ROWS;
    const int node = (int)(r0 >> 9);      // 512 rows per node, 8 blocks/node
    const int b0i  = (int)(r0 & 511);

    const int w  = t >> 6;
    const int l  = t & 63;
    const int lm = l & 31;
    const int q  = l >> 5;

    // R19: hoist half-0 b-frags to kernel entry — issued before any barrier,
    // in flight during staging + phase 2. Scheduler cannot sink across barriers.
    const short* __restrict__ bp = w1t + ((w << 5) + lm) * 256 + (q << 3);
    bf16x8 bv0[8];
#pragma unroll
    for (int j = 0; j < 8; j++) bv0[j] = *(const bf16x8*)&bp[16 * j];

    // stage 64 rows x 16 k as bf16 (k15 := 1.0 bias lane)
#pragma unroll
    for (int ii = 0; ii < 4; ii++) {
        int i = t + (ii << 8);
        int r = i >> 4, k = i & 15;
        float v = (k == 15) ? 1.0f : feat[r0 * 16 + i];
        __hip_bfloat16 h = __float2bfloat16(v);
        fTb[r * KF + k] = *reinterpret_cast<short*>(&h);
    }
    if (t < ROWS) lcs[t] = locg2[(size_t)node * 512 + b0i + t];
    __syncthreads();

    // feat B-frags (stable across halves)
    bf16x8 bfr0 = *(const bf16x8*)&fTb[lm * KF + (q << 3)];
    bf16x8 bfr1 = *(const bf16x8*)&fTb[(32 + lm) * KF + (q << 3)];

    f32x16 acc0 = {0.f, 0.f, 0.f, 0.f, 0.f, 0.f, 0.f, 0.f,
                   0.f, 0.f, 0.f, 0.f, 0.f, 0.f, 0.f, 0.f};
    f32x16 acc1 = acc0;

    // ---- half 0 ----
    {   // phase 2: wave w computes c-tile w*32 (global c in [0,128))
        const int c0g = (w << 5);
        bf16x8 afr = *(const bf16x8*)&w0te[(c0g + lm) * 16 + (q << 3)];
#pragma unroll
        for (int g = 0; g < 2; g++) {
            f32x16 ua = {0.f, 0.f, 0.f, 0.f, 0.f, 0.f, 0.f, 0.f,
                         0.f, 0.f, 0.f, 0.f, 0.f, 0.f, 0.f, 0.f};
            ua = __builtin_amdgcn_mfma_f32_32x32x16_bf16(afr, (g ? bfr1 : bfr0), ua, 0, 0, 0);
#pragma unroll
            for (int jj = 0; jj < 4; jj++) {
                int cl = (w << 5) + (q << 2) + (jj << 3);
                __hip_bfloat16 h0 = __float2bfloat16(fmaxf(ua[4 * jj + 0], 0.f));
                __hip_bfloat16 h1 = __float2bfloat16(fmaxf(ua[4 * jj + 1], 0.f));
                __hip_bfloat16 h2 = __float2bfloat16(fmaxf(ua[4 * jj + 2], 0.f));
                __hip_bfloat16 h3 = __float2bfloat16(fmaxf(ua[4 * jj + 3], 0.f));
                short4 pk = make_short4(*reinterpret_cast<short*>(&h0),
                                        *reinterpret_cast<short*>(&h1),
                                        *reinterpret_cast<short*>(&h2),
                                        *reinterpret_cast<short*>(&h3));
                *(short4*)&uB[(g * 32 + lm) * KSTR2 + cl] = pk;
            }
        }
    }
    __syncthreads();

    // hoist half-1 b-frags now — in flight during phase-3 half 0
    bf16x8 bv1[8];
#pragma unroll
    for (int j = 0; j < 8; j++) bv1[j] = *(const bf16x8*)&bp[128 + 16 * j];

    {   // phase 3 half 0: K = 0..127 from registers bv0 + LDS a-reads
        const short* __restrict__ ap0 = uB + lm * KSTR2 + (q << 3);
        const short* __restrict__ ap1 = uB + (32 + lm) * KSTR2 + (q << 3);
#pragma unroll
        for (int j = 0; j < 8; j++) {
            bf16x8 a0 = *(const bf16x8*)&ap0[16 * j];
            bf16x8 a1 = *(const bf16x8*)&ap1[16 * j];
            acc0 = __builtin_amdgcn_mfma_f32_32x32x16_bf16(a0, bv0[j], acc0, 0, 0, 0);
            acc1 = __builtin_amdgcn_mfma_f32_32x32x16_bf16(a1, bv0[j], acc1, 0, 0, 0);
        }
    }
    __syncthreads();   // drain uB reads before half-1 overwrites

    // ---- half 1 ----
    {   // phase 2: c-tile 128 + w*32
        const int c0g = 128 + (w << 5);
        bf16x8 afr = *(const bf16x8*)&w0te[(c0g + lm) * 16 + (q << 3)];
#pragma unroll
        for (int g = 0; g < 2; g++) {
            f32x16 ua = {0.f, 0.f, 0.f, 0.f, 0.f, 0.f, 0.f, 0.f,
                         0.f, 0.f, 0.f, 0.f, 0.f, 0.f, 0.f, 0.f};
            ua = __builtin_amdgcn_mfma_f32_32x32x16_bf16(afr, (g ? bfr1 : bfr0), ua, 0, 0, 0);
#pragma unroll
            for (int jj = 0; jj < 4; jj++) {
                int cl = (w << 5) + (q << 2) + (jj << 3);
                __hip_bfloat16 h0 = __float2bfloat16(fmaxf(ua[4 * jj + 0], 0.f));
                __hip_bfloat16 h1 = __float2bfloat16(fmaxf(ua[4 * jj + 1], 0.f));
                __hip_bfloat16 h2 = __float2bfloat16(fmaxf(ua[4 * jj + 2], 0.f));
                __hip_bfloat16 h3 = __float2bfloat16(fmaxf(ua[4 * jj + 3], 0.f));
                short4 pk = make_short4(*reinterpret_cast<short*>(&h0),
                                        *reinterpret_cast<short*>(&h1),
                                        *reinterpret_cast<short*>(&h2),
                                        *reinterpret_cast<short*>(&h3));
                *(short4*)&uB[(g * 32 + lm) * KSTR2 + cl] = pk;
            }
        }
    }
    __syncthreads();
    {   // phase 3 half 1: K = 128..255 from registers bv1 + LDS a-reads
        const short* __restrict__ ap0 = uB + lm * KSTR2 + (q << 3);
        const short* __restrict__ ap1 = uB + (32 + lm) * KSTR2 + (q << 3);
#pragma unroll
        for (int j = 0; j < 8; j++) {
            bf16x8 a0 = *(const bf16x8*)&ap0[16 * j];
            bf16x8 a1 = *(const bf16x8*)&ap1[16 * j];
            acc0 = __builtin_amdgcn_mfma_f32_32x32x16_bf16(a0, bv1[j], acc0, 0, 0, 0);
            acc1 = __builtin_amdgcn_mfma_f32_32x32x16_bf16(a1, bv1[j], acc1, 0, 0, 0);
        }
    }

    const int n_col = (w << 5) + lm;
    const float A = a1g[node];
    const float C = b1vg[node] * cs1[n_col] + b1[n_col];
    float s = 0.f, qq = 0.f;
#pragma unroll
    for (int g = 0; g < 2; g++) {
        const f32x16& acc = g ? acc1 : acc0;
#pragma unroll
        for (int r = 0; r < 16; r++) {
            int row = g * 32 + (r & 3) + ((r >> 2) << 3) + (q << 2);
            float x = fmaxf(fmaf(A, acc[r], C), 0.f);
            s += x; qq += x * x;
            unsigned char lc = lcs[row];
            if (lc != 255) xpk[(size_t)(((b0i + row) << 4) + lc) * 128 + n_col] = x;
        }
    }
    for (int off = 32; off > 0; off >>= 1) { s += __shfl_down(s, off, 64); qq += __shfl_down(qq, off, 64); }
    if (l == 0) { red[w] = s; red[4 + w] = qq; }
    __syncthreads();
    if (t == 0) {
        atomicAdd(&sum2[node],   red[0] + red[1] + red[2] + red[3]);
        atomicAdd(&sumsq2[node], red[4] + red[5] + red[6] + red[7]);
    }
}

// ---------------- Kernel E (R13): masked 2-layer GCN + mean, conv via MFMA, inline BN2 ----------------
__global__ __launch_bounds__(128) void kE(const float* __restrict__ xpk,
                                          const float* __restrict__ sum2, const float* __restrict__ sumsq2,
                                          const float* __restrict__ g2, const float* __restrict__ be2,
                                          const short* __restrict__ wct,
                                          const float* __restrict__ bc,
                                          const int* __restrict__ mcount, const int* __restrict__ mlist,
                                          const float* __restrict__ mdinv, const int* __restrict__ mecnt,
                                          const int* __restrict__ medge,
                                          float* __restrict__ out)
{
    __shared__ float xs[13 * 128];
    __shared__ float hs[16 * 128];
    __shared__ __align__(16) short xsb[16 * KS2];
    __shared__ float dv[13];
    __shared__ int   ml[13];
    __shared__ int   eg[64];
    __shared__ int   Ms, Es;
    const int b = blockIdx.x, j = threadIdx.x;
    if (j == 0) { Ms = mcount[b]; Es = mecnt[b]; }
    __syncthreads();
    const int M = Ms, E2 = (Es > 64) ? 64 : Es;
    if (j < 13) {
        if (j < M) { ml[j] = mlist[b * 16 + j]; dv[j] = mdinv[b * 16 + j]; }
        else dv[j] = 0.f;
    }
    for (int e = j; e < E2; e += 128) eg[e] = medge[b * 64 + e];
#pragma unroll
    for (int r = 13; r < 16; r++) xsb[r * KS2 + j] = 0;   // zero pad rows
    __syncthreads();
    // x = a2*x_pre + b2v at masked nodes (BN2 affine inline); bf16 copy into xsb
    const float cnt2 = 512.f * 128.f;
    for (int m = 0; m < 13; m++) {
        float v = 0.f;
        if (m < M) {
            int nn = ml[m];
            float mm = sum2[nn] / cnt2;
            float vv = fmaxf(sumsq2[nn] / cnt2 - mm * mm, 0.f);
            float aa = g2[nn] / sqrtf(vv + 1e-5f);
            float bb = be2[nn] - mm * aa;
            v = fmaf(aa, xpk[(size_t)((b << 4) + m) * 128 + j], bb);
        }
        xs[m * 128 + j] = v;
        __hip_bfloat16 h = __float2bfloat16(v);
        xsb[m * KS2 + j] = *reinterpret_cast<short*>(&h);
    }

    const int w = j >> 6, l = j & 63, lm = l & 15, q = l >> 4;

    for (int it = 0; it < 2; it++) {
        __syncthreads();   // xsb ready
        const short* __restrict__ wbase = wct + it * 16384;
        bf16x8 afr[4];
#pragma unroll
        for (int ks = 0; ks < 4; ks++)
            afr[ks] = *(const bf16x8*)&xsb[lm * KS2 + (ks << 5) + (q << 3)];
#pragma unroll
        for (int tt = 0; tt < 4; tt++) {
            const int n0 = ((w << 2) + tt) << 4;
            f32x4 a = {0.f, 0.f, 0.f, 0.f};
#pragma unroll
            for (int ks = 0; ks < 4; ks++) {
                bf16x8 bfr = *(const bf16x8*)&wbase[(n0 + lm) * 128 + (ks << 5) + (q << 3)];
                a = __builtin_amdgcn_mfma_f32_16x16x32_bf16(afr[ks], bfr, a, 0, 0, 0);
            }
#pragma unroll
            for (int r = 0; r < 4; r++) hs[((q << 2) + r) * 128 + n0 + lm] = a[r];
        }
        __syncthreads();   // hs ready; all xsb reads done
#pragma unroll
        for (int m = 0; m < 13; m++) xs[m * 128 + j] = dv[m] * dv[m] * hs[m * 128 + j];
        for (int e = 0; e < E2; e++) {
            int pr = eg[e] & 255, pc = eg[e] >> 8;
            xs[pc * 128 + j] += dv[pr] * dv[pc] * hs[pr * 128 + j];
        }
        float bcv = bc[it * 128 + j];
        for (int m = 0; m < M; m++) xs[m * 128 + j] += bcv;
        if (it == 0) {
#pragma unroll
            for (int m = 0; m < 13; m++) {
                __hip_bfloat16 h = __float2bfloat16(xs[m * 128 + j]);
                xsb[m * KS2 + j] = *reinterpret_cast<short*>(&h);
            }
        }
    }
    float sall = 0.f;
    for (int m = 0; m < M; m++) sall += xs[m * 128 + j];
    out[b * 128 + j] = sall / (float)M;
}

extern "C" void kernel_launch(void* const* d_in, const int* in_sizes, int n_in,
                              void* d_out, int out_size, void* d_ws, size_t ws_size,
                              hipStream_t stream)
{
    const float* agvs  = (const float*)d_in[0];
    const float* nodes = (const float*)d_in[1];
    const int*   ei    = (const int*)d_in[2];
    const float* W0    = (const float*)d_in[3];
    const float* b0    = (const float*)d_in[4];
    const float* g1    = (const float*)d_in[5];
    const float* be1   = (const float*)d_in[6];
    const float* W1    = (const float*)d_in[7];
    const float* b1    = (const float*)d_in[8];
    const float* g2    = (const float*)d_in[9];
    const float* be2   = (const float*)d_in[10];
    const float* Wc    = (const float*)d_in[11];
    const float* bc    = (const float*)d_in[12];
    const int E = in_sizes[2] / 2;

    char* ws = (char*)d_ws;
    float*          feat   = (float*)(ws + O_FEAT);
    float*          xpk    = (float*)(ws + O_XPK);
    float*          sum1   = (float*)(ws + O_STATS);
    float*          sum2   = sum1 + 2 * NB;
    float*          sumsq2 = sum1 + 3 * NB;
    float*          a1     = (float*)(ws + O_AB);
    float*          b1v    = a1 + NB;
    float*          cs1    = (float*)(ws + O_CS1);
    int*            mcount = (int*)(ws + O_MCNT);
    int*            mlist  = (int*)(ws + O_MLIST);
    float*          mdinv  = (float*)(ws + O_MDINV);
    int*            mecnt  = (int*)(ws + O_MECNT);
    int*            medge  = (int*)(ws + O_MEDGE);
    unsigned char*  locg2  = (unsigned char*)(ws + O_LOCG);
    short*          w1t    = (short*)(ws + O_W1T);
    short*          w0te   = (short*)(ws + O_W0TE);
    short*          wct    = (short*)(ws + O_WCT);

    kTA<<<785, 256, 0, stream>>>(agvs, nodes, ei, E, feat, mcount, mlist, mdinv, mecnt, medge,
                                 locg2, W1, W0, b0, Wc, w1t, w0te, wct, cs1, sum2);
    kB1<<<NB, 256, 0, stream>>>(feat, w0te, g1, be1, a1, b1v);
    kB2<<<(NB * BB) / ROWS, 256, 0, stream>>>(feat, w0te, w1t, b1, a1, b1v, cs1, locg2,
                                              xpk, sum2, sumsq2);
    kE<<<BB, 128, 0, stream>>>(xpk, sum2, sumsq2, g2, be2, wct, bc,
                               mcount, mlist, mdinv, mecnt, medge, (float*)d_out);
}

// Round 20
// 170.772 us; speedup vs baseline: 1.0323x; 1.0323x over previous
//
#include <hip/hip_runtime.h>
#include <hip/hip_bf16.h>

// GNNFeatureExtractor: B=512, N=400 nodes, E_DIM=128, hidden 256.
// Contract (established R0-R4): inputs f32 (edge_index int32), output f32.
// R20 = R18 (best: 172.6us; R19's register-hoist regressed 43->53us via
// occupancy loss) + ONE lever: kB2 launch_bounds (256,4)->(256,6).
// R18's LDS (21KB) and VGPR (36) permit 6-7 blocks/CU but the (256,4)
// declaration capped planning at 4 blocks/CU (measured 52% occ).
#define NB 400
#define BB 512
#define ROWS 64      // rows (n-major) per kB2 block
#define KSTR2 136    // uB row stride in bf16 (128 cols + 8 pad, 16B-aligned)
#define KF   24      // fTb row stride in bf16 (48B rows)
#define KS2  136     // xsb row stride in bf16 (kE)

typedef short  bf16x8 __attribute__((ext_vector_type(8)));   // 8 bf16 = 4 VGPRs
typedef float  f32x16 __attribute__((ext_vector_type(16)));
typedef float  f32x4  __attribute__((ext_vector_type(4)));

// ---- workspace layout (bytes), total ~17.9 MB ----
static constexpr size_t O_FEAT  = 0;            // f32 [400*512*16]  13,107,200
static constexpr size_t O_XPK   = 13107200;     // f32 [512*16*128]   4,194,304 packed masked x_pre
static constexpr size_t O_STATS = 17301504;     // f32 sum1/sq1/sum2/sq2 [400] each (sum2/sq2 used)
static constexpr size_t O_AB    = 17307904;     // f32 a1/b1v [400] each
static constexpr size_t O_CS1   = 17314304;     // f32 cs1[128]
static constexpr size_t O_MCNT  = 17314816;     // int mcount[512]
static constexpr size_t O_MLIST = 17316864;     // int mlist[512*16]
static constexpr size_t O_MDINV = 17349632;     // f32 mdinv[512*16]
static constexpr size_t O_MECNT = 17382400;     // int mecnt[512]
static constexpr size_t O_MEDGE = 17384448;     // int medge[512*64]
static constexpr size_t O_LOCG  = 17515520;     // u8  locg2[400*512] TRANSPOSED (255 = unmasked)
static constexpr size_t O_W1T   = 17720320;     // bf16 [128][256] transposed W1, 65,536
static constexpr size_t O_W0TE  = 17785856;     // bf16 [256][16] W0^T extended (k15=b0), 8,192
static constexpr size_t O_WCT   = 17794048;     // bf16 [2][128n][128k] transposed Wc, 65,536

// ---------------- Kernel TA: fused kT + kA + cs1 + stats-zero ----------------
__global__ __launch_bounds__(256) void kTA(const float* __restrict__ agvs,
                                           const float* __restrict__ nodes,
                                           const int* __restrict__ ei, int E,
                                           float* __restrict__ feat,
                                           int* __restrict__ mcount, int* __restrict__ mlist,
                                           float* __restrict__ mdinv, int* __restrict__ mecnt,
                                           int* __restrict__ medge,
                                           unsigned char* __restrict__ locg2,
                                           const float* __restrict__ W1,
                                           const float* __restrict__ W0,
                                           const float* __restrict__ b0,
                                           const float* __restrict__ Wc,
                                           short* __restrict__ w1t,
                                           short* __restrict__ w0te,
                                           short* __restrict__ wct,
                                           float* __restrict__ cs1,
                                           float* __restrict__ zstats)   // sum2 base, 800 f32
{
    const int t = threadIdx.x;
    if (blockIdx.x >= 512) {
        if (blockIdx.x < 784) {
            int i = (blockIdx.x - 512) * 256 + t;
            if (i < 32768) {
                int n = i >> 8, k = i & 255;
                __hip_bfloat16 h = __float2bfloat16(W1[k * 128 + n]);
                w1t[i] = *reinterpret_cast<short*>(&h);
            } else if (i < 36864) {
                int i2 = i - 32768;
                int c = i2 >> 4, k = i2 & 15;
                float v = (k == 15) ? b0[c] : W0[k * 256 + c];
                __hip_bfloat16 h = __float2bfloat16(v);
                w0te[i2] = *reinterpret_cast<short*>(&h);
            } else {
                int i2 = i - 36864;
                int it = i2 >> 14, rem = i2 & 16383, n = rem >> 7, k = rem & 127;
                __hip_bfloat16 h = __float2bfloat16(Wc[it * 16384 + k * 128 + n]);
                wct[i2] = *reinterpret_cast<short*>(&h);
            }
        } else {
            if (t < 128) {
                float s = 0.f;
                for (int c = 0; c < 256; c++) s += W1[c * 128 + t];
                cs1[t] = s;
            } else {
                for (int j = t - 128; j < 800; j += 128) zstats[j] = 0.f;
            }
        }
        return;
    }

    // ---- kA body ----
    __shared__ float nod[2 * NB];
    __shared__ float as_[160];
    __shared__ float fs[NB * 16];
    __shared__ int   idxs[70];
    __shared__ int   m0[NB], m1[NB], deg[NB], loc[NB];
    __shared__ unsigned long long bal[7];
    __shared__ int   pre[8];
    __shared__ int   ecnt;
    const int b = blockIdx.x;

    for (int i = t; i < 2 * NB; i += 256) nod[i] = nodes[i];
    for (int i = t; i < 160; i += 256)    as_[i] = agvs[b * 160 + i];
    for (int i = t; i < NB * 16; i += 256) fs[i] = 0.f;
    for (int i = t; i < NB; i += 256) m0[i] = 0;
    __syncthreads();

    // 70 argmins: strict '<' = np.argmin first-min.
    if (t < 70) {
        float cx, cy;
        if (t < 7) { cx = as_[2 + 2 * t]; cy = as_[3 + 2 * t]; }
        else { int a = (t - 7) / 7, k = (t - 7) % 7;
               cx = as_[16 * (a + 1) + 2 + 2 * k]; cy = as_[16 * (a + 1) + 3 + 2 * k]; }
        float bd = 3.4e38f; int bi = 0;
        for (int n = 0; n < NB; n++) {
            float dx = __fsub_rn(cx, nod[2 * n]);
            float dy = __fsub_rn(cy, nod[2 * n + 1]);
            float d  = __fadd_rn(__fmul_rn(dx, dx), __fmul_rn(dy, dy));
            if (d < bd) { bd = d; bi = n; }
        }
        idxs[t] = bi;
    }
    for (int n = t; n < NB; n += 256) {
        float dx = __fsub_rn(nod[2 * n],     as_[6]);
        float dy = __fsub_rn(nod[2 * n + 1], as_[7]);
        fs[n * 16 + 14] = __fsqrt_rn(__fadd_rn(__fmul_rn(dx, dx), __fmul_rn(dy, dy)));
    }
    __syncthreads();
    if (t < 70) {
        int col = (t < 7) ? t : 7 + ((t - 7) % 7);
        atomicAdd(&fs[idxs[t] * 16 + col], 1.0f);
    }
    if (t == 0) { m0[idxs[1]] = 1; ecnt = 0; }
    __syncthreads();

    for (int i = t; i < NB * 16; i += 256) {
        int n = i >> 4, k = i & 15;
        feat[(size_t)((n << 9) + b) * 16 + k] = fs[i];
    }

    for (int i = t; i < NB; i += 256) m1[i] = m0[i];
    __syncthreads();
    for (int e = t; e < E; e += 256) { int r = ei[e], c = ei[E + e]; if (m0[c]) m1[r] = 1; }
    __syncthreads();
    for (int i = t; i < NB; i += 256) m0[i] = m1[i];
    __syncthreads();
    for (int e = t; e < E; e += 256) { int r = ei[e], c = ei[E + e]; if (m1[c]) m0[r] = 1; }
    __syncthreads();
    for (int i = t; i < NB; i += 256) deg[i] = m0[i];
    __syncthreads();
    for (int e = t; e < E; e += 256) {
        int r = ei[e], c = ei[E + e];
        if (m0[r] && m0[c]) atomicAdd(&deg[c], 1);
    }
    __syncthreads();

    // parallel compaction via wave ballots
    for (int base = 0; base < 448; base += 256) {
        int i = base + t;
        bool m = (i < NB) && (m0[i] != 0);
        unsigned long long bm = __ballot(m);
        if ((t & 63) == 0 && (i >> 6) < 7) bal[i >> 6] = bm;
    }
    __syncthreads();
    if (t == 0) {
        int acc = 0;
        for (int c = 0; c < 7; c++) { pre[c] = acc; acc += __popcll(bal[c]); }
        mcount[b] = acc;
    }
    __syncthreads();
    for (int i = t; i < NB; i += 256) {
        if (m0[i]) {
            int c = i >> 6, l = i & 63;
            int rank = pre[c] + __popcll(bal[c] & ((1ull << l) - 1ull));
            loc[i] = rank;
            mlist[b * 16 + rank] = i;
            int d = deg[i]; if (d < 1) d = 1;
            mdinv[b * 16 + rank] = 1.0f / __fsqrt_rn((float)d);
        }
    }
    __syncthreads();
    for (int i = t; i < NB; i += 256)
        locg2[(size_t)i * 512 + b] = m0[i] ? (unsigned char)loc[i] : (unsigned char)255;
    for (int e = t; e < E; e += 256) {
        int r = ei[e], c = ei[E + e];
        if (m0[r] && m0[c]) {
            int s = atomicAdd(&ecnt, 1);
            if (s < 64) medge[b * 64 + s] = loc[r] | (loc[c] << 8);
        }
    }
    __syncthreads();
    if (t == 0) mecnt[b] = ecnt;
}

// ---------------- Kernel B1 (R13): BN1 stats via MFMA + inline BN1 affine ----------------
__global__ __launch_bounds__(256) void kB1(const float* __restrict__ feat,
                                           const short* __restrict__ w0te,
                                           const float* __restrict__ g1, const float* __restrict__ be1,
                                           float* __restrict__ a1, float* __restrict__ b1v)
{
    __shared__ __align__(16) short fTb[512 * KF];   // 24,576 B
    __shared__ float red[8];
    const int n = blockIdx.x, t = threadIdx.x;
    for (int i = t; i < 512 * 8; i += 256) {
        int r = i >> 3, kk = (i & 7) << 1;
        float2 v = *(const float2*)&feat[(size_t)n * 8192 + r * 16 + kk];
        if (kk == 14) v.y = 1.0f;
        __hip_bfloat16 h0 = __float2bfloat16(v.x), h1 = __float2bfloat16(v.y);
        unsigned int pk = (unsigned int)(unsigned short)*reinterpret_cast<short*>(&h0) |
                          ((unsigned int)(unsigned short)*reinterpret_cast<short*>(&h1) << 16);
        *(unsigned int*)&fTb[r * KF + kk] = pk;
    }
    __syncthreads();

    const int w = t >> 6, l = t & 63, lm = l & 31, q = l >> 5;
    bf16x8 afr[8];
#pragma unroll
    for (int ct = 0; ct < 8; ct++)
        afr[ct] = *(const bf16x8*)&w0te[((ct << 5) + lm) * 16 + (q << 3)];

    float s = 0.f, q2 = 0.f;
#pragma unroll
    for (int ch = 0; ch < 4; ch++) {
        const int row = (((w << 2) + ch) << 5) + lm;
        bf16x8 bfr = *(const bf16x8*)&fTb[row * KF + (q << 3)];
#pragma unroll
        for (int ct = 0; ct < 8; ct++) {
            f32x16 ua = {0.f, 0.f, 0.f, 0.f, 0.f, 0.f, 0.f, 0.f,
                         0.f, 0.f, 0.f, 0.f, 0.f, 0.f, 0.f, 0.f};
            ua = __builtin_amdgcn_mfma_f32_32x32x16_bf16(afr[ct], bfr, ua, 0, 0, 0);
#pragma unroll
            for (int r = 0; r < 16; r++) {
                float x = fmaxf(ua[r], 0.f);
                s += x; q2 = fmaf(x, x, q2);
            }
        }
    }
    for (int off = 32; off > 0; off >>= 1) { s += __shfl_down(s, off, 64); q2 += __shfl_down(q2, off, 64); }
    if (l == 0) { red[w] = s; red[4 + w] = q2; }
    __syncthreads();
    if (t == 0) {
        float S = red[0] + red[1] + red[2] + red[3];
        float Q = red[4] + red[5] + red[6] + red[7];
        const float cnt = 512.f * 256.f;
        float m = S / cnt;
        float v = fmaxf(Q / cnt - m * m, 0.f);
        float a = g1[n] / sqrtf(v + 1e-5f);
        a1[n]  = a;
        b1v[n] = be1[n] - m * a;
    }
}

// ---------------- Kernel B2 (R20): 64-row, 2 chains, K-split, launch_bounds(256,6) ----------------
__global__ __launch_bounds__(256, 6) void kB2(const float* __restrict__ feat,
                                           const short* __restrict__ w0te,
                                           const short* __restrict__ w1t,
                                           const float* __restrict__ b1,
                                           const float* __restrict__ a1g, const float* __restrict__ b1vg,
                                           const float* __restrict__ cs1,
                                           const unsigned char* __restrict__ locg2,
                                           float* __restrict__ xpk,
                                           float* __restrict__ sum2, float* __restrict__ sumsq2)
{
    __shared__ __align__(16) short fTb[ROWS * KF];     // 3,072 B
    __shared__ __align__(16) short uB[ROWS * KSTR2];   // 17,408 B (one K-half of u)
    __shared__ unsigned char lcs[ROWS];
    __shared__ float red[8];
    const int t = threadIdx.x;
    const size_t r0 = (size_t)blockIdx.x * ROWS;
    const int node = (int)(r0 >> 9);      // 512 rows per node, 8 blocks/node
    const int b0i  = (int)(r0 & 511);

    // stage 64 rows x 16 k as bf16 (k15 := 1.0 bias lane)
#pragma unroll
    for (int ii = 0; ii < 4; ii++) {
        int i = t + (ii << 8);
        int r = i >> 4, k = i & 15;
        float v = (k == 15) ? 1.0f : feat[r0 * 16 + i];
        __hip_bfloat16 h = __float2bfloat16(v);
        fTb[r * KF + k] = *reinterpret_cast<short*>(&h);
    }
    if (t < ROWS) lcs[t] = locg2[(size_t)node * 512 + b0i + t];
    __syncthreads();

    const int w  = t >> 6;
    const int l  = t & 63;
    const int lm = l & 31;
    const int q  = l >> 5;

    // hoisted: feat B-frags (stable across halves)
    bf16x8 bfr0 = *(const bf16x8*)&fTb[lm * KF + (q << 3)];
    bf16x8 bfr1 = *(const bf16x8*)&fTb[(32 + lm) * KF + (q << 3)];

    f32x16 acc0 = {0.f, 0.f, 0.f, 0.f, 0.f, 0.f, 0.f, 0.f,
                   0.f, 0.f, 0.f, 0.f, 0.f, 0.f, 0.f, 0.f};
    f32x16 acc1 = acc0;

#pragma unroll
    for (int h = 0; h < 2; h++) {
        // phase 2 (half h): wave w computes c-tile c0g = h*128 + w*32
        {
            const int c0g = (h << 7) + (w << 5);
            bf16x8 afr = *(const bf16x8*)&w0te[(c0g + lm) * 16 + (q << 3)];
#pragma unroll
            for (int g = 0; g < 2; g++) {
                f32x16 ua = {0.f, 0.f, 0.f, 0.f, 0.f, 0.f, 0.f, 0.f,
                             0.f, 0.f, 0.f, 0.f, 0.f, 0.f, 0.f, 0.f};
                ua = __builtin_amdgcn_mfma_f32_32x32x16_bf16(afr, (g ? bfr1 : bfr0), ua, 0, 0, 0);
#pragma unroll
                for (int jj = 0; jj < 4; jj++) {
                    int cl = (w << 5) + (q << 2) + (jj << 3);   // local col in [0,128)
                    __hip_bfloat16 h0 = __float2bfloat16(fmaxf(ua[4 * jj + 0], 0.f));
                    __hip_bfloat16 h1 = __float2bfloat16(fmaxf(ua[4 * jj + 1], 0.f));
                    __hip_bfloat16 h2 = __float2bfloat16(fmaxf(ua[4 * jj + 2], 0.f));
                    __hip_bfloat16 h3 = __float2bfloat16(fmaxf(ua[4 * jj + 3], 0.f));
                    short4 pk = make_short4(*reinterpret_cast<short*>(&h0),
                                            *reinterpret_cast<short*>(&h1),
                                            *reinterpret_cast<short*>(&h2),
                                            *reinterpret_cast<short*>(&h3));
                    *(short4*)&uB[(g * 32 + lm) * KSTR2 + cl] = pk;
                }
            }
        }
        __syncthreads();
        // phase 3 (half h): accumulate K = h*128 .. h*128+127
        const short* __restrict__ bp  = w1t + ((w << 5) + lm) * 256 + (q << 3) + (h << 7);
        const short* __restrict__ ap0 = uB + lm * KSTR2 + (q << 3);
        const short* __restrict__ ap1 = uB + (32 + lm) * KSTR2 + (q << 3);
#pragma unroll
        for (int k0 = 0; k0 < 128; k0 += 16) {
            bf16x8 bv = *(const bf16x8*)&bp[k0];
            bf16x8 a0 = *(const bf16x8*)&ap0[k0];
            bf16x8 a1 = *(const bf16x8*)&ap1[k0];
            acc0 = __builtin_amdgcn_mfma_f32_32x32x16_bf16(a0, bv, acc0, 0, 0, 0);
            acc1 = __builtin_amdgcn_mfma_f32_32x32x16_bf16(a1, bv, acc1, 0, 0, 0);
        }
        if (h == 0) __syncthreads();   // drain reads before half-1 overwrites uB
    }

    const int n_col = (w << 5) + lm;
    const float A = a1g[node];
    const float C = b1vg[node] * cs1[n_col] + b1[n_col];
    float s = 0.f, qq = 0.f;
#pragma unroll
    for (int g = 0; g < 2; g++) {
        const f32x16& acc = g ? acc1 : acc0;
#pragma unroll
        for (int r = 0; r < 16; r++) {
            int row = g * 32 + (r & 3) + ((r >> 2) << 3) + (q << 2);
            float x = fmaxf(fmaf(A, acc[r], C), 0.f);
            s += x; qq += x * x;
            unsigned char lc = lcs[row];
            if (lc != 255) xpk[(size_t)(((b0i + row) << 4) + lc) * 128 + n_col] = x;
        }
    }
    for (int off = 32; off > 0; off >>= 1) { s += __shfl_down(s, off, 64); qq += __shfl_down(qq, off, 64); }
    if (l == 0) { red[w] = s; red[4 + w] = qq; }
    __syncthreads();
    if (t == 0) {
        atomicAdd(&sum2[node],   red[0] + red[1] + red[2] + red[3]);
        atomicAdd(&sumsq2[node], red[4] + red[5] + red[6] + red[7]);
    }
}

// ---------------- Kernel E (R13): masked 2-layer GCN + mean, conv via MFMA, inline BN2 ----------------
__global__ __launch_bounds__(128) void kE(const float* __restrict__ xpk,
                                          const float* __restrict__ sum2, const float* __restrict__ sumsq2,
                                          const float* __restrict__ g2, const float* __restrict__ be2,
                                          const short* __restrict__ wct,
                                          const float* __restrict__ bc,
                                          const int* __restrict__ mcount, const int* __restrict__ mlist,
                                          const float* __restrict__ mdinv, const int* __restrict__ mecnt,
                                          const int* __restrict__ medge,
                                          float* __restrict__ out)
{
    __shared__ float xs[13 * 128];
    __shared__ float hs[16 * 128];
    __shared__ __align__(16) short xsb[16 * KS2];
    __shared__ float dv[13];
    __shared__ int   ml[13];
    __shared__ int   eg[64];
    __shared__ int   Ms, Es;
    const int b = blockIdx.x, j = threadIdx.x;
    if (j == 0) { Ms = mcount[b]; Es = mecnt[b]; }
    __syncthreads();
    const int M = Ms, E2 = (Es > 64) ? 64 : Es;
    if (j < 13) {
        if (j < M) { ml[j] = mlist[b * 16 + j]; dv[j] = mdinv[b * 16 + j]; }
        else dv[j] = 0.f;
    }
    for (int e = j; e < E2; e += 128) eg[e] = medge[b * 64 + e];
#pragma unroll
    for (int r = 13; r < 16; r++) xsb[r * KS2 + j] = 0;   // zero pad rows
    __syncthreads();
    // x = a2*x_pre + b2v at masked nodes (BN2 affine inline); bf16 copy into xsb
    const float cnt2 = 512.f * 128.f;
    for (int m = 0; m < 13; m++) {
        float v = 0.f;
        if (m < M) {
            int nn = ml[m];
            float mm = sum2[nn] / cnt2;
            float vv = fmaxf(sumsq2[nn] / cnt2 - mm * mm, 0.f);
            float aa = g2[nn] / sqrtf(vv + 1e-5f);
            float bb = be2[nn] - mm * aa;
            v = fmaf(aa, xpk[(size_t)((b << 4) + m) * 128 + j], bb);
        }
        xs[m * 128 + j] = v;
        __hip_bfloat16 h = __float2bfloat16(v);
        xsb[m * KS2 + j] = *reinterpret_cast<short*>(&h);
    }

    const int w = j >> 6, l = j & 63, lm = l & 15, q = l >> 4;

    for (int it = 0; it < 2; it++) {
        __syncthreads();   // xsb ready
        const short* __restrict__ wbase = wct + it * 16384;
        bf16x8 afr[4];
#pragma unroll
        for (int ks = 0; ks < 4; ks++)
            afr[ks] = *(const bf16x8*)&xsb[lm * KS2 + (ks << 5) + (q << 3)];
#pragma unroll
        for (int tt = 0; tt < 4; tt++) {
            const int n0 = ((w << 2) + tt) << 4;
            f32x4 a = {0.f, 0.f, 0.f, 0.f};
#pragma unroll
            for (int ks = 0; ks < 4; ks++) {
                bf16x8 bfr = *(const bf16x8*)&wbase[(n0 + lm) * 128 + (ks << 5) + (q << 3)];
                a = __builtin_amdgcn_mfma_f32_16x16x32_bf16(afr[ks], bfr, a, 0, 0, 0);
            }
#pragma unroll
            for (int r = 0; r < 4; r++) hs[((q << 2) + r) * 128 + n0 + lm] = a[r];
        }
        __syncthreads();   // hs ready; all xsb reads done
#pragma unroll
        for (int m = 0; m < 13; m++) xs[m * 128 + j] = dv[m] * dv[m] * hs[m * 128 + j];
        for (int e = 0; e < E2; e++) {
            int pr = eg[e] & 255, pc = eg[e] >> 8;
            xs[pc * 128 + j] += dv[pr] * dv[pc] * hs[pr * 128 + j];
        }
        float bcv = bc[it * 128 + j];
        for (int m = 0; m < M; m++) xs[m * 128 + j] += bcv;
        if (it == 0) {
#pragma unroll
            for (int m = 0; m < 13; m++) {
                __hip_bfloat16 h = __float2bfloat16(xs[m * 128 + j]);
                xsb[m * KS2 + j] = *reinterpret_cast<short*>(&h);
            }
        }
    }
    float sall = 0.f;
    for (int m = 0; m < M; m++) sall += xs[m * 128 + j];
    out[b * 128 + j] = sall / (float)M;
}

extern "C" void kernel_launch(void* const* d_in, const int* in_sizes, int n_in,
                              void* d_out, int out_size, void* d_ws, size_t ws_size,
                              hipStream_t stream)
{
    const float* agvs  = (const float*)d_in[0];
    const float* nodes = (const float*)d_in[1];
    const int*   ei    = (const int*)d_in[2];
    const float* W0    = (const float*)d_in[3];
    const float* b0    = (const float*)d_in[4];
    const float* g1    = (const float*)d_in[5];
    const float* be1   = (const float*)d_in[6];
    const float* W1    = (const float*)d_in[7];
    const float* b1    = (const float*)d_in[8];
    const float* g2    = (const float*)d_in[9];
    const float* be2   = (const float*)d_in[10];
    const float* Wc    = (const float*)d_in[11];
    const float* bc    = (const float*)d_in[12];
    const int E = in_sizes[2] / 2;

    char* ws = (char*)d_ws;
    float*          feat   = (float*)(ws + O_FEAT);
    float*          xpk    = (float*)(ws + O_XPK);
    float*          sum1   = (float*)(ws + O_STATS);
    float*          sum2   = sum1 + 2 * NB;
    float*          sumsq2 = sum1 + 3 * NB;
    float*          a1     = (float*)(ws + O_AB);
    float*          b1v    = a1 + NB;
    float*          cs1    = (float*)(ws + O_CS1);
    int*            mcount = (int*)(ws + O_MCNT);
    int*            mlist  = (int*)(ws + O_MLIST);
    float*          mdinv  = (float*)(ws + O_MDINV);
    int*            mecnt  = (int*)(ws + O_MECNT);
    int*            medge  = (int*)(ws + O_MEDGE);
    unsigned char*  locg2  = (unsigned char*)(ws + O_LOCG);
    short*          w1t    = (short*)(ws + O_W1T);
    short*          w0te   = (short*)(ws + O_W0TE);
    short*          wct    = (short*)(ws + O_WCT);

    kTA<<<785, 256, 0, stream>>>(agvs, nodes, ei, E, feat, mcount, mlist, mdinv, mecnt, medge,
                                 locg2, W1, W0, b0, Wc, w1t, w0te, wct, cs1, sum2);
    kB1<<<NB, 256, 0, stream>>>(feat, w0te, g1, be1, a1, b1v);
    kB2<<<(NB * BB) / ROWS, 256, 0, stream>>>(feat, w0te, w1t, b1, a1, b1v, cs1, locg2,
                                              xpk, sum2, sumsq2);
    kE<<<BB, 128, 0, stream>>>(xpk, sum2, sumsq2, g2, be2, wct, bc,
                               mcount, mlist, mdinv, mecnt, medge, (float*)d_out);
}

// Round 21
// 168.698 us; speedup vs baseline: 1.0450x; 1.0123x over previous
//
#include <hip/hip_runtime.h>
#include <hip/hip_bf16.h>

// GNNFeatureExtractor: B=512, N=400 nodes, E_DIM=128, hidden 256.
// Contract (established R0-R4): inputs f32 (edge_index int32), output f32.
// R21 = R20 + ONE lever: feat stored as bf16 with bias lane baked (k15=1.0).
// kA converts once (conversion commutes -> bit-identical results); kB1/kB2
// staging become pure int4 copies (half bytes, no cvt). Everything else = R20.
#define NB 400
#define BB 512
#define ROWS 64      // rows (n-major) per kB2 block
#define KSTR2 136    // uB row stride in bf16 (128 cols + 8 pad, 16B-aligned)
#define KF   24      // fTb row stride in bf16 (48B rows)
#define KS2  136     // xsb row stride in bf16 (kE)

typedef short  bf16x8 __attribute__((ext_vector_type(8)));   // 8 bf16 = 4 VGPRs
typedef float  f32x16 __attribute__((ext_vector_type(16)));
typedef float  f32x4  __attribute__((ext_vector_type(4)));

// ---- workspace layout (bytes) ----
static constexpr size_t O_FEAT  = 0;            // bf16 [400*512*16]  6,553,600 (R21: was f32)
static constexpr size_t O_XPK   = 13107200;     // f32 [512*16*128]   4,194,304 packed masked x_pre
static constexpr size_t O_STATS = 17301504;     // f32 sum1/sq1/sum2/sq2 [400] each (sum2/sq2 used)
static constexpr size_t O_AB    = 17307904;     // f32 a1/b1v [400] each
static constexpr size_t O_CS1   = 17314304;     // f32 cs1[128]
static constexpr size_t O_MCNT  = 17314816;     // int mcount[512]
static constexpr size_t O_MLIST = 17316864;     // int mlist[512*16]
static constexpr size_t O_MDINV = 17349632;     // f32 mdinv[512*16]
static constexpr size_t O_MECNT = 17382400;     // int mecnt[512]
static constexpr size_t O_MEDGE = 17384448;     // int medge[512*64]
static constexpr size_t O_LOCG  = 17515520;     // u8  locg2[400*512] TRANSPOSED (255 = unmasked)
static constexpr size_t O_W1T   = 17720320;     // bf16 [128][256] transposed W1, 65,536
static constexpr size_t O_W0TE  = 17785856;     // bf16 [256][16] W0^T extended (k15=b0), 8,192
static constexpr size_t O_WCT   = 17794048;     // bf16 [2][128n][128k] transposed Wc, 65,536

// ---------------- Kernel TA: fused kT + kA + cs1 + stats-zero ----------------
__global__ __launch_bounds__(256) void kTA(const float* __restrict__ agvs,
                                           const float* __restrict__ nodes,
                                           const int* __restrict__ ei, int E,
                                           short* __restrict__ featb,
                                           int* __restrict__ mcount, int* __restrict__ mlist,
                                           float* __restrict__ mdinv, int* __restrict__ mecnt,
                                           int* __restrict__ medge,
                                           unsigned char* __restrict__ locg2,
                                           const float* __restrict__ W1,
                                           const float* __restrict__ W0,
                                           const float* __restrict__ b0,
                                           const float* __restrict__ Wc,
                                           short* __restrict__ w1t,
                                           short* __restrict__ w0te,
                                           short* __restrict__ wct,
                                           float* __restrict__ cs1,
                                           float* __restrict__ zstats)   // sum2 base, 800 f32
{
    const int t = threadIdx.x;
    if (blockIdx.x >= 512) {
        if (blockIdx.x < 784) {
            int i = (blockIdx.x - 512) * 256 + t;
            if (i < 32768) {
                int n = i >> 8, k = i & 255;
                __hip_bfloat16 h = __float2bfloat16(W1[k * 128 + n]);
                w1t[i] = *reinterpret_cast<short*>(&h);
            } else if (i < 36864) {
                int i2 = i - 32768;
                int c = i2 >> 4, k = i2 & 15;
                float v = (k == 15) ? b0[c] : W0[k * 256 + c];
                __hip_bfloat16 h = __float2bfloat16(v);
                w0te[i2] = *reinterpret_cast<short*>(&h);
            } else {
                int i2 = i - 36864;
                int it = i2 >> 14, rem = i2 & 16383, n = rem >> 7, k = rem & 127;
                __hip_bfloat16 h = __float2bfloat16(Wc[it * 16384 + k * 128 + n]);
                wct[i2] = *reinterpret_cast<short*>(&h);
            }
        } else {
            if (t < 128) {
                float s = 0.f;
                for (int c = 0; c < 256; c++) s += W1[c * 128 + t];
                cs1[t] = s;
            } else {
                for (int j = t - 128; j < 800; j += 128) zstats[j] = 0.f;
            }
        }
        return;
    }

    // ---- kA body ----
    __shared__ float nod[2 * NB];
    __shared__ float as_[160];
    __shared__ float fs[NB * 16];
    __shared__ int   idxs[70];
    __shared__ int   m0[NB], m1[NB], deg[NB], loc[NB];
    __shared__ unsigned long long bal[7];
    __shared__ int   pre[8];
    __shared__ int   ecnt;
    const int b = blockIdx.x;

    for (int i = t; i < 2 * NB; i += 256) nod[i] = nodes[i];
    for (int i = t; i < 160; i += 256)    as_[i] = agvs[b * 160 + i];
    for (int i = t; i < NB * 16; i += 256) fs[i] = 0.f;
    for (int i = t; i < NB; i += 256) m0[i] = 0;
    __syncthreads();

    // 70 argmins: strict '<' = np.argmin first-min.
    if (t < 70) {
        float cx, cy;
        if (t < 7) { cx = as_[2 + 2 * t]; cy = as_[3 + 2 * t]; }
        else { int a = (t - 7) / 7, k = (t - 7) % 7;
               cx = as_[16 * (a + 1) + 2 + 2 * k]; cy = as_[16 * (a + 1) + 3 + 2 * k]; }
        float bd = 3.4e38f; int bi = 0;
        for (int n = 0; n < NB; n++) {
            float dx = __fsub_rn(cx, nod[2 * n]);
            float dy = __fsub_rn(cy, nod[2 * n + 1]);
            float d  = __fadd_rn(__fmul_rn(dx, dx), __fmul_rn(dy, dy));
            if (d < bd) { bd = d; bi = n; }
        }
        idxs[t] = bi;
    }
    for (int n = t; n < NB; n += 256) {
        float dx = __fsub_rn(nod[2 * n],     as_[6]);
        float dy = __fsub_rn(nod[2 * n + 1], as_[7]);
        fs[n * 16 + 14] = __fsqrt_rn(__fadd_rn(__fmul_rn(dx, dx), __fmul_rn(dy, dy)));
    }
    __syncthreads();
    if (t < 70) {
        int col = (t < 7) ? t : 7 + ((t - 7) % 7);
        atomicAdd(&fs[idxs[t] * 16 + col], 1.0f);
    }
    if (t == 0) { m0[idxs[1]] = 1; ecnt = 0; }
    __syncthreads();

    // write feat node-major as bf16, bias lane k15 := 1.0
    for (int i = t; i < NB * 16; i += 256) {
        int n = i >> 4, k = i & 15;
        float v = (k == 15) ? 1.0f : fs[i];
        __hip_bfloat16 h = __float2bfloat16(v);
        featb[(size_t)((n << 9) + b) * 16 + k] = *reinterpret_cast<short*>(&h);
    }

    for (int i = t; i < NB; i += 256) m1[i] = m0[i];
    __syncthreads();
    for (int e = t; e < E; e += 256) { int r = ei[e], c = ei[E + e]; if (m0[c]) m1[r] = 1; }
    __syncthreads();
    for (int i = t; i < NB; i += 256) m0[i] = m1[i];
    __syncthreads();
    for (int e = t; e < E; e += 256) { int r = ei[e], c = ei[E + e]; if (m1[c]) m0[r] = 1; }
    __syncthreads();
    for (int i = t; i < NB; i += 256) deg[i] = m0[i];
    __syncthreads();
    for (int e = t; e < E; e += 256) {
        int r = ei[e], c = ei[E + e];
        if (m0[r] && m0[c]) atomicAdd(&deg[c], 1);
    }
    __syncthreads();

    // parallel compaction via wave ballots
    for (int base = 0; base < 448; base += 256) {
        int i = base + t;
        bool m = (i < NB) && (m0[i] != 0);
        unsigned long long bm = __ballot(m);
        if ((t & 63) == 0 && (i >> 6) < 7) bal[i >> 6] = bm;
    }
    __syncthreads();
    if (t == 0) {
        int acc = 0;
        for (int c = 0; c < 7; c++) { pre[c] = acc; acc += __popcll(bal[c]); }
        mcount[b] = acc;
    }
    __syncthreads();
    for (int i = t; i < NB; i += 256) {
        if (m0[i]) {
            int c = i >> 6, l = i & 63;
            int rank = pre[c] + __popcll(bal[c] & ((1ull << l) - 1ull));
            loc[i] = rank;
            mlist[b * 16 + rank] = i;
            int d = deg[i]; if (d < 1) d = 1;
            mdinv[b * 16 + rank] = 1.0f / __fsqrt_rn((float)d);
        }
    }
    __syncthreads();
    for (int i = t; i < NB; i += 256)
        locg2[(size_t)i * 512 + b] = m0[i] ? (unsigned char)loc[i] : (unsigned char)255;
    for (int e = t; e < E; e += 256) {
        int r = ei[e], c = ei[E + e];
        if (m0[r] && m0[c]) {
            int s = atomicAdd(&ecnt, 1);
            if (s < 64) medge[b * 64 + s] = loc[r] | (loc[c] << 8);
        }
    }
    __syncthreads();
    if (t == 0) mecnt[b] = ecnt;
}

// ---------------- Kernel B1: BN1 stats via MFMA + inline BN1 affine (bf16 feat copy) ----------------
__global__ __launch_bounds__(256) void kB1(const short* __restrict__ featb,
                                           const short* __restrict__ w0te,
                                           const float* __restrict__ g1, const float* __restrict__ be1,
                                           float* __restrict__ a1, float* __restrict__ b1v)
{
    __shared__ __align__(16) short fTb[512 * KF];   // 24,576 B
    __shared__ float red[8];
    const int n = blockIdx.x, t = threadIdx.x;
    // pure copy: bias lane already baked by kA
    for (int i = t; i < 1024; i += 256) {
        int r = i >> 1, half = i & 1;
        *(int4*)&fTb[r * KF + (half << 3)] =
            *(const int4*)&featb[(size_t)n * 8192 + r * 16 + (half << 3)];
    }
    __syncthreads();

    const int w = t >> 6, l = t & 63, lm = l & 31, q = l >> 5;
    bf16x8 afr[8];
#pragma unroll
    for (int ct = 0; ct < 8; ct++)
        afr[ct] = *(const bf16x8*)&w0te[((ct << 5) + lm) * 16 + (q << 3)];

    float s = 0.f, q2 = 0.f;
#pragma unroll
    for (int ch = 0; ch < 4; ch++) {
        const int row = (((w << 2) + ch) << 5) + lm;
        bf16x8 bfr = *(const bf16x8*)&fTb[row * KF + (q << 3)];
#pragma unroll
        for (int ct = 0; ct < 8; ct++) {
            f32x16 ua = {0.f, 0.f, 0.f, 0.f, 0.f, 0.f, 0.f, 0.f,
                         0.f, 0.f, 0.f, 0.f, 0.f, 0.f, 0.f, 0.f};
            ua = __builtin_amdgcn_mfma_f32_32x32x16_bf16(afr[ct], bfr, ua, 0, 0, 0);
#pragma unroll
            for (int r = 0; r < 16; r++) {
                float x = fmaxf(ua[r], 0.f);
                s += x; q2 = fmaf(x, x, q2);
            }
        }
    }
    for (int off = 32; off > 0; off >>= 1) { s += __shfl_down(s, off, 64); q2 += __shfl_down(q2, off, 64); }
    if (l == 0) { red[w] = s; red[4 + w] = q2; }
    __syncthreads();
    if (t == 0) {
        float S = red[0] + red[1] + red[2] + red[3];
        float Q = red[4] + red[5] + red[6] + red[7];
        const float cnt = 512.f * 256.f;
        float m = S / cnt;
        float v = fmaxf(Q / cnt - m * m, 0.f);
        float a = g1[n] / sqrtf(v + 1e-5f);
        a1[n]  = a;
        b1v[n] = be1[n] - m * a;
    }
}

// ---------------- Kernel B2 (R21): 64-row, 2 chains, K-split, bf16 feat copy ----------------
__global__ __launch_bounds__(256, 6) void kB2(const short* __restrict__ featb,
                                           const short* __restrict__ w0te,
                                           const short* __restrict__ w1t,
                                           const float* __restrict__ b1,
                                           const float* __restrict__ a1g, const float* __restrict__ b1vg,
                                           const float* __restrict__ cs1,
                                           const unsigned char* __restrict__ locg2,
                                           float* __restrict__ xpk,
                                           float* __restrict__ sum2, float* __restrict__ sumsq2)
{
    __shared__ __align__(16) short fTb[ROWS * KF];     // 3,072 B
    __shared__ __align__(16) short uB[ROWS * KSTR2];   // 17,408 B (one K-half of u)
    __shared__ unsigned char lcs[ROWS];
    __shared__ float red[8];
    const int t = threadIdx.x;
    const size_t r0 = (size_t)blockIdx.x * ROWS;
    const int node = (int)(r0 >> 9);      // 512 rows per node, 8 blocks/node
    const int b0i  = (int)(r0 & 511);

    // stage 64 rows: pure int4 copy (bias lane baked)
    if (t < 128) {
        int r = t >> 1, half = t & 1;
        *(int4*)&fTb[r * KF + (half << 3)] =
            *(const int4*)&featb[(r0 + r) * 16 + (half << 3)];
    }
    if (t < ROWS) lcs[t] = locg2[(size_t)node * 512 + b0i + t];
    __syncthreads();

    const int w  = t >> 6;
    const int l  = t & 63;
    const int lm = l & 31;
    const int q  = l >> 5;

    // hoisted: feat B-frags (stable across halves)
    bf16x8 bfr0 = *(const bf16x8*)&fTb[lm * KF + (q << 3)];
    bf16x8 bfr1 = *(const bf16x8*)&fTb[(32 + lm) * KF + (q << 3)];

    f32x16 acc0 = {0.f, 0.f, 0.f, 0.f, 0.f, 0.f, 0.f, 0.f,
                   0.f, 0.f, 0.f, 0.f, 0.f, 0.f, 0.f, 0.f};
    f32x16 acc1 = acc0;

#pragma unroll
    for (int h = 0; h < 2; h++) {
        // phase 2 (half h): wave w computes c-tile c0g = h*128 + w*32
        {
            const int c0g = (h << 7) + (w << 5);
            bf16x8 afr = *(const bf16x8*)&w0te[(c0g + lm) * 16 + (q << 3)];
#pragma unroll
            for (int g = 0; g < 2; g++) {
                f32x16 ua = {0.f, 0.f, 0.f, 0.f, 0.f, 0.f, 0.f, 0.f,
                             0.f, 0.f, 0.f, 0.f, 0.f, 0.f, 0.f, 0.f};
                ua = __builtin_amdgcn_mfma_f32_32x32x16_bf16(afr, (g ? bfr1 : bfr0), ua, 0, 0, 0);
#pragma unroll
                for (int jj = 0; jj < 4; jj++) {
                    int cl = (w << 5) + (q << 2) + (jj << 3);   // local col in [0,128)
                    __hip_bfloat16 h0 = __float2bfloat16(fmaxf(ua[4 * jj + 0], 0.f));
                    __hip_bfloat16 h1 = __float2bfloat16(fmaxf(ua[4 * jj + 1], 0.f));
                    __hip_bfloat16 h2 = __float2bfloat16(fmaxf(ua[4 * jj + 2], 0.f));
                    __hip_bfloat16 h3 = __float2bfloat16(fmaxf(ua[4 * jj + 3], 0.f));
                    short4 pk = make_short4(*reinterpret_cast<short*>(&h0),
                                            *reinterpret_cast<short*>(&h1),
                                            *reinterpret_cast<short*>(&h2),
                                            *reinterpret_cast<short*>(&h3));
                    *(short4*)&uB[(g * 32 + lm) * KSTR2 + cl] = pk;
                }
            }
        }
        __syncthreads();
        // phase 3 (half h): accumulate K = h*128 .. h*128+127
        const short* __restrict__ bp  = w1t + ((w << 5) + lm) * 256 + (q << 3) + (h << 7);
        const short* __restrict__ ap0 = uB + lm * KSTR2 + (q << 3);
        const short* __restrict__ ap1 = uB + (32 + lm) * KSTR2 + (q << 3);
#pragma unroll
        for (int k0 = 0; k0 < 128; k0 += 16) {
            bf16x8 bv = *(const bf16x8*)&bp[k0];
            bf16x8 a0 = *(const bf16x8*)&ap0[k0];
            bf16x8 a1 = *(const bf16x8*)&ap1[k0];
            acc0 = __builtin_amdgcn_mfma_f32_32x32x16_bf16(a0, bv, acc0, 0, 0, 0);
            acc1 = __builtin_amdgcn_mfma_f32_32x32x16_bf16(a1, bv, acc1, 0, 0, 0);
        }
        if (h == 0) __syncthreads();   // drain reads before half-1 overwrites uB
    }

    const int n_col = (w << 5) + lm;
    const float A = a1g[node];
    const float C = b1vg[node] * cs1[n_col] + b1[n_col];
    float s = 0.f, qq = 0.f;
#pragma unroll
    for (int g = 0; g < 2; g++) {
        const f32x16& acc = g ? acc1 : acc0;
#pragma unroll
        for (int r = 0; r < 16; r++) {
            int row = g * 32 + (r & 3) + ((r >> 2) << 3) + (q << 2);
            float x = fmaxf(fmaf(A, acc[r], C), 0.f);
            s += x; qq += x * x;
            unsigned char lc = lcs[row];
            if (lc != 255) xpk[(size_t)(((b0i + row) << 4) + lc) * 128 + n_col] = x;
        }
    }
    for (int off = 32; off > 0; off >>= 1) { s += __shfl_down(s, off, 64); qq += __shfl_down(qq, off, 64); }
    if (l == 0) { red[w] = s; red[4 + w] = qq; }
    __syncthreads();
    if (t == 0) {
        atomicAdd(&sum2[node],   red[0] + red[1] + red[2] + red[3]);
        atomicAdd(&sumsq2[node], red[4] + red[5] + red[6] + red[7]);
    }
}

// ---------------- Kernel E (R13): masked 2-layer GCN + mean, conv via MFMA, inline BN2 ----------------
__global__ __launch_bounds__(128) void kE(const float* __restrict__ xpk,
                                          const float* __restrict__ sum2, const float* __restrict__ sumsq2,
                                          const float* __restrict__ g2, const float* __restrict__ be2,
                                          const short* __restrict__ wct,
                                          const float* __restrict__ bc,
                                          const int* __restrict__ mcount, const int* __restrict__ mlist,
                                          const float* __restrict__ mdinv, const int* __restrict__ mecnt,
                                          const int* __restrict__ medge,
                                          float* __restrict__ out)
{
    __shared__ float xs[13 * 128];
    __shared__ float hs[16 * 128];
    __shared__ __align__(16) short xsb[16 * KS2];
    __shared__ float dv[13];
    __shared__ int   ml[13];
    __shared__ int   eg[64];
    __shared__ int   Ms, Es;
    const int b = blockIdx.x, j = threadIdx.x;
    if (j == 0) { Ms = mcount[b]; Es = mecnt[b]; }
    __syncthreads();
    const int M = Ms, E2 = (Es > 64) ? 64 : Es;
    if (j < 13) {
        if (j < M) { ml[j] = mlist[b * 16 + j]; dv[j] = mdinv[b * 16 + j]; }
        else dv[j] = 0.f;
    }
    for (int e = j; e < E2; e += 128) eg[e] = medge[b * 64 + e];
#pragma unroll
    for (int r = 13; r < 16; r++) xsb[r * KS2 + j] = 0;   // zero pad rows
    __syncthreads();
    // x = a2*x_pre + b2v at masked nodes (BN2 affine inline); bf16 copy into xsb
    const float cnt2 = 512.f * 128.f;
    for (int m = 0; m < 13; m++) {
        float v = 0.f;
        if (m < M) {
            int nn = ml[m];
            float mm = sum2[nn] / cnt2;
            float vv = fmaxf(sumsq2[nn] / cnt2 - mm * mm, 0.f);
            float aa = g2[nn] / sqrtf(vv + 1e-5f);
            float bb = be2[nn] - mm * aa;
            v = fmaf(aa, xpk[(size_t)((b << 4) + m) * 128 + j], bb);
        }
        xs[m * 128 + j] = v;
        __hip_bfloat16 h = __float2bfloat16(v);
        xsb[m * KS2 + j] = *reinterpret_cast<short*>(&h);
    }

    const int w = j >> 6, l = j & 63, lm = l & 15, q = l >> 4;

    for (int it = 0; it < 2; it++) {
        __syncthreads();   // xsb ready
        const short* __restrict__ wbase = wct + it * 16384;
        bf16x8 afr[4];
#pragma unroll
        for (int ks = 0; ks < 4; ks++)
            afr[ks] = *(const bf16x8*)&xsb[lm * KS2 + (ks << 5) + (q << 3)];
#pragma unroll
        for (int tt = 0; tt < 4; tt++) {
            const int n0 = ((w << 2) + tt) << 4;
            f32x4 a = {0.f, 0.f, 0.f, 0.f};
#pragma unroll
            for (int ks = 0; ks < 4; ks++) {
                bf16x8 bfr = *(const bf16x8*)&wbase[(n0 + lm) * 128 + (ks << 5) + (q << 3)];
                a = __builtin_amdgcn_mfma_f32_16x16x32_bf16(afr[ks], bfr, a, 0, 0, 0);
            }
#pragma unroll
            for (int r = 0; r < 4; r++) hs[((q << 2) + r) * 128 + n0 + lm] = a[r];
        }
        __syncthreads();   // hs ready; all xsb reads done
#pragma unroll
        for (int m = 0; m < 13; m++) xs[m * 128 + j] = dv[m] * dv[m] * hs[m * 128 + j];
        for (int e = 0; e < E2; e++) {
            int pr = eg[e] & 255, pc = eg[e] >> 8;
            xs[pc * 128 + j] += dv[pr] * dv[pc] * hs[pr * 128 + j];
        }
        float bcv = bc[it * 128 + j];
        for (int m = 0; m < M; m++) xs[m * 128 + j] += bcv;
        if (it == 0) {
#pragma unroll
            for (int m = 0; m < 13; m++) {
                __hip_bfloat16 h = __float2bfloat16(xs[m * 128 + j]);
                xsb[m * KS2 + j] = *reinterpret_cast<short*>(&h);
            }
        }
    }
    float sall = 0.f;
    for (int m = 0; m < M; m++) sall += xs[m * 128 + j];
    out[b * 128 + j] = sall / (float)M;
}

extern "C" void kernel_launch(void* const* d_in, const int* in_sizes, int n_in,
                              void* d_out, int out_size, void* d_ws, size_t ws_size,
                              hipStream_t stream)
{
    const float* agvs  = (const float*)d_in[0];
    const float* nodes = (const float*)d_in[1];
    const int*   ei    = (const int*)d_in[2];
    const float* W0    = (const float*)d_in[3];
    const float* b0    = (const float*)d_in[4];
    const float* g1    = (const float*)d_in[5];
    const float* be1   = (const float*)d_in[6];
    const float* W1    = (const float*)d_in[7];
    const float* b1    = (const float*)d_in[8];
    const float* g2    = (const float*)d_in[9];
    const float* be2   = (const float*)d_in[10];
    const float* Wc    = (const float*)d_in[11];
    const float* bc    = (const float*)d_in[12];
    const int E = in_sizes[2] / 2;

    char* ws = (char*)d_ws;
    short*          featb  = (short*)(ws + O_FEAT);
    float*          xpk    = (float*)(ws + O_XPK);
    float*          sum1   = (float*)(ws + O_STATS);
    float*          sum2   = sum1 + 2 * NB;
    float*          sumsq2 = sum1 + 3 * NB;
    float*          a1     = (float*)(ws + O_AB);
    float*          b1v    = a1 + NB;
    float*          cs1    = (float*)(ws + O_CS1);
    int*            mcount = (int*)(ws + O_MCNT);
    int*            mlist  = (int*)(ws + O_MLIST);
    float*          mdinv  = (float*)(ws + O_MDINV);
    int*            mecnt  = (int*)(ws + O_MECNT);
    int*            medge  = (int*)(ws + O_MEDGE);
    unsigned char*  locg2  = (unsigned char*)(ws + O_LOCG);
    short*          w1t    = (short*)(ws + O_W1T);
    short*          w0te   = (short*)(ws + O_W0TE);
    short*          wct    = (short*)(ws + O_WCT);

    kTA<<<785, 256, 0, stream>>>(agvs, nodes, ei, E, featb, mcount, mlist, mdinv, mecnt, medge,
                                 locg2, W1, W0, b0, Wc, w1t, w0te, wct, cs1, sum2);
    kB1<<<NB, 256, 0, stream>>>(featb, w0te, g1, be1, a1, b1v);
    kB2<<<(NB * BB) / ROWS, 256, 0, stream>>>(featb, w0te, w1t, b1, a1, b1v, cs1, locg2,
                                              xpk, sum2, sumsq2);
    kE<<<BB, 128, 0, stream>>>(xpk, sum2, sumsq2, g2, be2, wct, bc,
                               mcount, mlist, mdinv, mecnt, medge, (float*)d_out);
}